// Round 3
// baseline (205.661 us; speedup 1.0000x reference)
//
#include <hip/hip_runtime.h>

#define SEQ   2048
#define BATCH 32
#define INF   256
#define NST   512
#define OUTF  256
#define CLEN  32
#define NCH   (SEQ / CLEN)   /* 64 chunks */

typedef __bf16 bf16;
typedef __bf16 bf16x8 __attribute__((ext_vector_type(8)));
typedef float  f32x4  __attribute__((ext_vector_type(4)));

// ---------------------------------------------------------------------------
// K1: lambda = exp(-exp(ll)); lamL = lambda^CLEN; B' = gamma*B (bf16); C (bf16)
// ---------------------------------------------------------------------------
__global__ void k_prep(const float* __restrict__ ll,
                       const float* __restrict__ Bm,
                       const float* __restrict__ Cm,
                       float* __restrict__ lam,
                       float* __restrict__ lamL,
                       bf16* __restrict__ Bb,
                       bf16* __restrict__ Cb) {
  int i = blockIdx.x * 256 + threadIdx.x;
  if (i < NST) {
    float lmb = expf(-expf(ll[i]));
    lam[i] = lmb;
    float p = lmb;
#pragma unroll
    for (int q = 0; q < 5; ++q) p *= p;   // lambda^32
    lamL[i] = p;
  }
  if (i < NST * INF) {
    int n = i >> 8;
    float lmb = expf(-expf(ll[n]));
    float g = sqrtf(1.0f - lmb * lmb + 1e-7f);
    Bb[i] = (bf16)(Bm[i] * g);
  }
  if (i < OUTF * NST) {
    Cb[i] = (bf16)(Cm[i]);
  }
}

// ---------------------------------------------------------------------------
// stage x chunk -> LDS bf16, XOR swizzle byte ^= (row&15)<<4  (row = t)
// ---------------------------------------------------------------------------
__device__ __forceinline__ void stage_x(const float* __restrict__ xp,
                                        char* xs, int tid) {
#pragma unroll
  for (int rep = 0; rep < 4; ++rep) {
    int slot = rep * 512 + tid;          // 0..2047 float4 slots
    int row = slot >> 6, col4 = slot & 63;
    float4 v = *(const float4*)(xp + (size_t)row * (BATCH * INF) + col4 * 4);
    union { bf16 h[4]; unsigned long long u; } pk;
    pk.h[0] = (bf16)v.x; pk.h[1] = (bf16)v.y;
    pk.h[2] = (bf16)v.z; pk.h[3] = (bf16)v.w;
    int byte = (row * (INF * 2) + col4 * 8) ^ ((row & 15) << 4);
    *(unsigned long long*)(xs + byte) = pk.u;
  }
}

// ---------------------------------------------------------------------------
// PASS (templated): stage x -> GEMM1 (acc in regs) -> in-register shfl scan.
// FULL=0: write Z only.  FULL=1: states -> ss (bf16, swz) -> GEMM2 -> out.
// Fragment map (verified): lane holds (t = mt*16 + kg*4 + r, n = n0+nt*16+rl)
// ---------------------------------------------------------------------------
template <int FULL>
__global__ __launch_bounds__(512, 5)
void k_pass(const float* __restrict__ x, const bf16* __restrict__ Bb,
            const bf16* __restrict__ Cb, const float* __restrict__ lam,
            const float* __restrict__ S0, float* __restrict__ Z,
            float* __restrict__ out, float* __restrict__ fin) {
  __shared__ __align__(16) char xs[CLEN * INF * 2];                 // 16KB
  __shared__ __align__(16) char ss[FULL ? (CLEN * NST * 2) : 16];   // 32KB if FULL

  const int c = blockIdx.x, b = blockIdx.y, tid = threadIdx.x;
  const int wid = tid >> 6, lane = tid & 63;
  const int rl = lane & 15, kg = lane >> 4;
  const int n0 = wid * 64;

  stage_x(x + ((size_t)(c * CLEN) * BATCH + b) * INF, xs, tid);
  __syncthreads();

  // ---- GEMM1: acc[mt][nt] , wave owns n-panel [n0, n0+64)
  f32x4 acc[2][4] = {};
#pragma unroll
  for (int k0 = 0; k0 < INF; k0 += 32) {
    bf16x8 af[2], bfr[4];
#pragma unroll
    for (int mt = 0; mt < 2; ++mt) {
      int row = mt * 16 + rl;
      int byte = (row * (INF * 2) + (k0 + kg * 8) * 2) ^ ((rl) << 4);
      af[mt] = *(const bf16x8*)(xs + byte);
    }
#pragma unroll
    for (int nt = 0; nt < 4; ++nt)
      bfr[nt] = *(const bf16x8*)(Bb + (size_t)(n0 + nt * 16 + rl) * INF + k0 + kg * 8);
#pragma unroll
    for (int mt = 0; mt < 2; ++mt)
#pragma unroll
      for (int nt = 0; nt < 4; ++nt)
        acc[mt][nt] = __builtin_amdgcn_mfma_f32_16x16x32_bf16(af[mt], bfr[nt], acc[mt][nt], 0, 0, 0);
  }

  // ---- in-register segmented scan over t (32 steps spread over kg lanes)
  // acc[mt][nt][r] is b at (t, n); overwrite with full state s at (t, n).
#pragma unroll
  for (int nt = 0; nt < 4; ++nt) {
    const int n = n0 + nt * 16 + rl;
    const float la = lam[n];
    const float l2 = la * la, l3 = l2 * la, l4 = l2 * l2, l8 = l4 * l4;
    const float p4k = ((kg & 1) ? l4 : 1.0f) * ((kg & 2) ? l8 : 1.0f); // la^(4*kg)
    float carry = FULL ? S0[((size_t)c * BATCH + b) * NST + n] : 0.0f;
#pragma unroll
    for (int mt = 0; mt < 2; ++mt) {
      // local inclusive scan within the lane's 4-t segment
      float sl0 = acc[mt][nt][0];
      float sl1 = fmaf(la, sl0, acc[mt][nt][1]);
      float sl2 = fmaf(la, sl1, acc[mt][nt][2]);
      float sl3 = fmaf(la, sl2, acc[mt][nt][3]);
      // Hillis-Steele over kg segments with decay la^4
      float E = sl3;
      float g1 = __shfl_up(E, 16);
      float G = (kg >= 1) ? fmaf(l4, g1, E) : E;
      float g2 = __shfl_up(G, 32);
      G = (kg >= 2) ? fmaf(l8, g2, G) : G;
      float X = __shfl_up(G, 16);
      X = (kg >= 1) ? X : 0.0f;
      float cin = fmaf(p4k, carry, X);   // full state at segment start - 1
      float s0 = fmaf(la, cin, sl0);
      float s1 = fmaf(l2, cin, sl1);
      float s2 = fmaf(l3, cin, sl2);
      float s3 = fmaf(l4, cin, sl3);
      acc[mt][nt][0] = s0; acc[mt][nt][1] = s1;
      acc[mt][nt][2] = s2; acc[mt][nt][3] = s3;
      // carry into next mt-half: state at t = mt*16+15 (lane kg==3, same rl)
      carry = __shfl(s3, rl + 48);
    }
    if (!FULL) {
      if (kg == 3)   // lane holds t=31 in acc[1][nt][3] == carry
        Z[((size_t)c * BATCH + b) * NST + n] = acc[1][nt][3];
    } else {
      if (kg == 3 && c == NCH - 1)
        fin[(size_t)b * NST + n] = acc[1][nt][3];
    }
  }

  if (!FULL) return;

  // ---- states -> ss (bf16, [t][n], byte ^= (t&15)<<4)
#pragma unroll
  for (int mt = 0; mt < 2; ++mt)
#pragma unroll
    for (int nt = 0; nt < 4; ++nt)
#pragma unroll
      for (int r = 0; r < 4; ++r) {
        int t = mt * 16 + kg * 4 + r;
        int n = n0 + nt * 16 + rl;
        int byte = (t * (NST * 2) + n * 2) ^ ((t & 15) << 4);
        *(bf16*)(ss + byte) = (bf16)acc[mt][nt][r];
      }
  __syncthreads();

  // ---- GEMM2: out[t][o] = sum_n s[t][n] * C[o][n]; wave owns o-panel [wid*32,..)
  {
    const int o0 = wid * 32;
    f32x4 a2[2][2] = {};
#pragma unroll
    for (int k0 = 0; k0 < NST; k0 += 32) {
      bf16x8 af[2], cf[2];
#pragma unroll
      for (int mt = 0; mt < 2; ++mt) {
        int t = mt * 16 + rl;
        int byte = (t * (NST * 2) + (k0 + kg * 8) * 2) ^ ((rl) << 4);
        af[mt] = *(const bf16x8*)(ss + byte);
      }
#pragma unroll
      for (int ot = 0; ot < 2; ++ot)
        cf[ot] = *(const bf16x8*)(Cb + (size_t)(o0 + ot * 16 + rl) * NST + k0 + kg * 8);
#pragma unroll
      for (int mt = 0; mt < 2; ++mt)
#pragma unroll
        for (int ot = 0; ot < 2; ++ot)
          a2[mt][ot] = __builtin_amdgcn_mfma_f32_16x16x32_bf16(af[mt], cf[ot], a2[mt][ot], 0, 0, 0);
    }
#pragma unroll
    for (int mt = 0; mt < 2; ++mt)
#pragma unroll
      for (int ot = 0; ot < 2; ++ot)
#pragma unroll
        for (int r = 0; r < 4; ++r) {
          int t = mt * 16 + kg * 4 + r;
          int o = o0 + ot * 16 + rl;
          out[(((size_t)(c * CLEN + t)) * BATCH + b) * OUTF + o] = a2[mt][ot][r];
        }
  }
}

// ---------------------------------------------------------------------------
// K3: exclusive prefix over chunks:  S0[c] = lamL*S0[c-1] + Z[c-1],  S0[0]=0
// ---------------------------------------------------------------------------
__global__ __launch_bounds__(128)
void k_chain(const float* __restrict__ Z, const float* __restrict__ lamL,
             float* __restrict__ S0) {
  const int b = blockIdx.x;
  const int n = blockIdx.y * 128 + threadIdx.x;
  const float lL = lamL[n];
  float z[NCH];
#pragma unroll
  for (int c = 0; c < NCH; ++c)
    z[c] = Z[((size_t)c * BATCH + b) * NST + n];
  float s = 0.0f;
#pragma unroll
  for (int c = 0; c < NCH; ++c) {
    S0[((size_t)c * BATCH + b) * NST + n] = s;
    s = fmaf(lL, s, z[c]);
  }
}

// ---------------------------------------------------------------------------
extern "C" void kernel_launch(void* const* d_in, const int* in_sizes, int n_in,
                              void* d_out, int out_size, void* d_ws, size_t ws_size,
                              hipStream_t stream) {
  const float* x  = (const float*)d_in[0];
  const float* ll = (const float*)d_in[1];
  const float* Bm = (const float*)d_in[2];
  const float* Cm = (const float*)d_in[3];

  char* ws = (char*)d_ws;
  float* lam  = (float*)(ws);
  float* lamL = (float*)(ws + 2048);
  bf16*  Bb   = (bf16*)(ws + 4096);
  bf16*  Cb   = (bf16*)(ws + 4096 + NST * INF * 2);
  float* Z    = (float*)(ws + 4096 + NST * INF * 2 + OUTF * NST * 2);
  float* S0   = (float*)((char*)Z + (size_t)NCH * BATCH * NST * 4);
  // total ws use: ~8.6 MB

  float* out = (float*)d_out;
  float* fin = out + (size_t)SEQ * BATCH * OUTF;

  k_prep<<<dim3(512), dim3(256), 0, stream>>>(ll, Bm, Cm, lam, lamL, Bb, Cb);
  k_pass<0><<<dim3(NCH, BATCH), dim3(512), 0, stream>>>(x, Bb, Cb, lam, S0, Z, out, fin);
  k_chain<<<dim3(BATCH, 4), dim3(128), 0, stream>>>(Z, lamL, S0);
  k_pass<1><<<dim3(NCH, BATCH), dim3(512), 0, stream>>>(x, Bb, Cb, lam, S0, Z, out, fin);
}

// Round 4
// 186.124 us; speedup vs baseline: 1.1050x; 1.1050x over previous
//
#include <hip/hip_runtime.h>

#define SEQ   2048
#define BATCH 32
#define INF   256
#define NST   512
#define OUTF  256
#define CLEN  32
#define NCH   64
#define NJOB  4
#define NCG   (NCH / NJOB)          /* 16 chunk-groups */
#define NBLK  (NCG * BATCH)         /* 512 blocks = 2/CU */

typedef __bf16 bf16;
typedef __bf16 bf16x8 __attribute__((ext_vector_type(8)));
typedef float  f32x4  __attribute__((ext_vector_type(4)));

// ---------------------------------------------------------------------------
// K1: lambda = exp(-exp(ll)); lamL = lambda^CLEN; B' = gamma*B (bf16); C (bf16)
// ---------------------------------------------------------------------------
__global__ void k_prep(const float* __restrict__ ll,
                       const float* __restrict__ Bm,
                       const float* __restrict__ Cm,
                       float* __restrict__ lam,
                       float* __restrict__ lamL,
                       bf16* __restrict__ Bb,
                       bf16* __restrict__ Cb) {
  int i = blockIdx.x * 256 + threadIdx.x;
  if (i < NST) {
    float lmb = expf(-expf(ll[i]));
    lam[i] = lmb;
    float p = lmb;
#pragma unroll
    for (int q = 0; q < 5; ++q) p *= p;   // lambda^32
    lamL[i] = p;
  }
  if (i < NST * INF) {
    int n = i >> 8;
    float lmb = expf(-expf(ll[n]));
    float g = sqrtf(1.0f - lmb * lmb + 1e-7f);
    Bb[i] = (bf16)(Bm[i] * g);
  }
  if (i < OUTF * NST) {
    Cb[i] = (bf16)(Cm[i]);
  }
}

// ---------------------------------------------------------------------------
// x chunk staging split: load to regs (issue early) / cvt+ds_write (late)
// LDS layout: [t][i] bf16, byte = (t*512 + i*2) ^ ((t&15)<<4)
// ---------------------------------------------------------------------------
__device__ __forceinline__ void xload(const float* __restrict__ xp, int tid,
                                      float4 xr[4]) {
#pragma unroll
  for (int rep = 0; rep < 4; ++rep) {
    int slot = rep * 512 + tid;
    int row = slot >> 6, col4 = slot & 63;
    xr[rep] = *(const float4*)(xp + (size_t)row * (BATCH * INF) + col4 * 4);
  }
}

__device__ __forceinline__ void xstore(char* xsb, int tid, const float4 xr[4]) {
#pragma unroll
  for (int rep = 0; rep < 4; ++rep) {
    int slot = rep * 512 + tid;
    int row = slot >> 6, col4 = slot & 63;
    union { bf16 h[4]; unsigned long long u; } pk;
    pk.h[0] = (bf16)xr[rep].x; pk.h[1] = (bf16)xr[rep].y;
    pk.h[2] = (bf16)xr[rep].z; pk.h[3] = (bf16)xr[rep].w;
    int byte = (row * (INF * 2) + col4 * 8) ^ ((row & 15) << 4);
    *(unsigned long long*)(xsb + byte) = pk.u;
  }
}

// ---------------------------------------------------------------------------
// Persistent pass: block = (b, cg); 4 chunks; B' in regs; dbuf x staging.
// FULL=0: Z only.  FULL=1: states -> ss -> GEMM2 -> out (+fin).
// ---------------------------------------------------------------------------
template <int FULL>
__global__ __launch_bounds__(512)
void k_pass(const float* __restrict__ x, const bf16* __restrict__ Bb,
            const bf16* __restrict__ Cb, const float* __restrict__ lam,
            const float* __restrict__ S0, float* __restrict__ Z,
            float* __restrict__ out, float* __restrict__ fin) {
  __shared__ __align__(16) char xs[2][CLEN * INF * 2];              // 2x16KB
  __shared__ __align__(16) char ss[FULL ? (CLEN * NST * 2) : 16];   // 32KB if FULL

  const int tid = threadIdx.x, wid = tid >> 6, lane = tid & 63;
  const int rl = lane & 15, kg = lane >> 4;
  const int b = blockIdx.x >> 4, cg = blockIdx.x & 15;
  const int n0 = wid * 64;

  // hoisted per-n decay constants
  float la[4], l2[4], l3[4], l4[4], l8[4], p4k[4];
#pragma unroll
  for (int nt = 0; nt < 4; ++nt) {
    float v = lam[n0 + nt * 16 + rl];
    la[nt] = v; l2[nt] = v * v; l3[nt] = l2[nt] * v;
    l4[nt] = l2[nt] * l2[nt]; l8[nt] = l4[nt] * l4[nt];
    p4k[nt] = ((kg & 1) ? l4[nt] : 1.0f) * ((kg & 2) ? l8[nt] : 1.0f);
  }

  // B' panel into registers (reused by all 4 jobs)
  bf16x8 Breg[8][4];
#pragma unroll
  for (int k = 0; k < 8; ++k)
#pragma unroll
    for (int nt = 0; nt < 4; ++nt)
      Breg[k][nt] = *(const bf16x8*)(Bb + (size_t)(n0 + nt * 16 + rl) * INF + k * 32 + kg * 8);

  // prologue: stage job 0
  {
    float4 xr0[4];
    xload(x + ((size_t)(cg * NJOB * CLEN) * BATCH + b) * INF, tid, xr0);
    xstore(xs[0], tid, xr0);
  }
  __syncthreads();

#pragma unroll
  for (int jj = 0; jj < NJOB; ++jj) {
    const int c = cg * NJOB + jj;

    // issue next chunk's x loads early (latency hides under compute)
    float4 xr[4];
    if (jj < NJOB - 1)
      xload(x + ((size_t)((c + 1) * CLEN) * BATCH + b) * INF, tid, xr);

    // S0 prefetch (FULL)
    float carry[4];
#pragma unroll
    for (int nt = 0; nt < 4; ++nt)
      carry[nt] = FULL ? S0[((size_t)c * BATCH + b) * NST + n0 + nt * 16 + rl] : 0.0f;

    // ---- GEMM1 (pure ds_read + MFMA; B in regs)
    f32x4 acc[2][4] = {};
#pragma unroll
    for (int k = 0; k < 8; ++k) {
      bf16x8 af[2];
#pragma unroll
      for (int mt = 0; mt < 2; ++mt) {
        int row = mt * 16 + rl;
        int byte = (row * (INF * 2) + (k * 32 + kg * 8) * 2) ^ (rl << 4);
        af[mt] = *(const bf16x8*)(&xs[jj & 1][0] + byte);
      }
#pragma unroll
      for (int mt = 0; mt < 2; ++mt)
#pragma unroll
        for (int nt = 0; nt < 4; ++nt)
          acc[mt][nt] = __builtin_amdgcn_mfma_f32_16x16x32_bf16(af[mt], Breg[k][nt], acc[mt][nt], 0, 0, 0);
    }

    // ---- in-register scan, step-parallel across nt (4 independent chains)
#pragma unroll
    for (int mt = 0; mt < 2; ++mt) {
      float sl[4][4];
#pragma unroll
      for (int nt = 0; nt < 4; ++nt) {
        sl[nt][0] = acc[mt][nt][0];
        sl[nt][1] = fmaf(la[nt], sl[nt][0], acc[mt][nt][1]);
        sl[nt][2] = fmaf(la[nt], sl[nt][1], acc[mt][nt][2]);
        sl[nt][3] = fmaf(la[nt], sl[nt][2], acc[mt][nt][3]);
      }
      float G[4];
#pragma unroll
      for (int nt = 0; nt < 4; ++nt) {
        float g1 = __shfl_up(sl[nt][3], 16);
        G[nt] = (kg >= 1) ? fmaf(l4[nt], g1, sl[nt][3]) : sl[nt][3];
      }
#pragma unroll
      for (int nt = 0; nt < 4; ++nt) {
        float g2 = __shfl_up(G[nt], 32);
        G[nt] = (kg >= 2) ? fmaf(l8[nt], g2, G[nt]) : G[nt];
      }
#pragma unroll
      for (int nt = 0; nt < 4; ++nt) {
        float X = __shfl_up(G[nt], 16);
        X = (kg >= 1) ? X : 0.0f;
        float cin = fmaf(p4k[nt], carry[nt], X);
        acc[mt][nt][0] = fmaf(la[nt], cin, sl[nt][0]);
        acc[mt][nt][1] = fmaf(l2[nt], cin, sl[nt][1]);
        acc[mt][nt][2] = fmaf(l3[nt], cin, sl[nt][2]);
        acc[mt][nt][3] = fmaf(l4[nt], cin, sl[nt][3]);
      }
#pragma unroll
      for (int nt = 0; nt < 4; ++nt)
        carry[nt] = __shfl(acc[mt][nt][3], rl + 48);
    }

    if (!FULL) {
      if (kg == 3)
#pragma unroll
        for (int nt = 0; nt < 4; ++nt)
          Z[((size_t)c * BATCH + b) * NST + n0 + nt * 16 + rl] = acc[1][nt][3];
      if (jj < NJOB - 1) {
        xstore(xs[(jj + 1) & 1], tid, xr);
        __syncthreads();
      }
    } else {
      if (c == NCH - 1 && kg == 3)
#pragma unroll
        for (int nt = 0; nt < 4; ++nt)
          fin[(size_t)b * NST + n0 + nt * 16 + rl] = acc[1][nt][3];

      __syncthreads();   // A: previous job's GEMM2 done reading ss
      // states -> ss (bf16, swizzled)
#pragma unroll
      for (int mt = 0; mt < 2; ++mt)
#pragma unroll
        for (int nt = 0; nt < 4; ++nt)
#pragma unroll
          for (int r = 0; r < 4; ++r) {
            int t = mt * 16 + kg * 4 + r;
            int n = n0 + nt * 16 + rl;
            int byte = (t * (NST * 2) + n * 2) ^ ((t & 15) << 4);
            *(bf16*)(&ss[0] + byte) = (bf16)acc[mt][nt][r];
          }
      if (jj < NJOB - 1) xstore(xs[(jj + 1) & 1], tid, xr);
      __syncthreads();   // B: ss (and next xs) ready

      // ---- GEMM2: out[t][o] = sum_n s[t][n] * C[o][n]
      const int o0 = wid * 32;
      f32x4 a2[2][2] = {};
#pragma unroll
      for (int k0 = 0; k0 < NST; k0 += 32) {
        bf16x8 af[2], cf[2];
#pragma unroll
        for (int mt = 0; mt < 2; ++mt) {
          int t = mt * 16 + rl;
          int byte = (t * (NST * 2) + (k0 + kg * 8) * 2) ^ (rl << 4);
          af[mt] = *(const bf16x8*)(&ss[0] + byte);
        }
#pragma unroll
        for (int ot = 0; ot < 2; ++ot)
          cf[ot] = *(const bf16x8*)(Cb + (size_t)(o0 + ot * 16 + rl) * NST + k0 + kg * 8);
#pragma unroll
        for (int mt = 0; mt < 2; ++mt)
#pragma unroll
          for (int ot = 0; ot < 2; ++ot)
            a2[mt][ot] = __builtin_amdgcn_mfma_f32_16x16x32_bf16(af[mt], cf[ot], a2[mt][ot], 0, 0, 0);
      }
#pragma unroll
      for (int mt = 0; mt < 2; ++mt)
#pragma unroll
        for (int ot = 0; ot < 2; ++ot)
#pragma unroll
          for (int r = 0; r < 4; ++r) {
            int t = mt * 16 + kg * 4 + r;
            int o = o0 + ot * 16 + rl;
            out[(((size_t)(c * CLEN + t)) * BATCH + b) * OUTF + o] = a2[mt][ot][r];
          }
    }
  }
}

// ---------------------------------------------------------------------------
// K3: exclusive prefix over chunks:  S0[c] = lamL*S0[c-1] + Z[c-1],  S0[0]=0
// ---------------------------------------------------------------------------
__global__ __launch_bounds__(128)
void k_chain(const float* __restrict__ Z, const float* __restrict__ lamL,
             float* __restrict__ S0) {
  const int b = blockIdx.x;
  const int n = blockIdx.y * 128 + threadIdx.x;
  const float lL = lamL[n];
  float z[NCH];
#pragma unroll
  for (int c = 0; c < NCH; ++c)
    z[c] = Z[((size_t)c * BATCH + b) * NST + n];
  float s = 0.0f;
#pragma unroll
  for (int c = 0; c < NCH; ++c) {
    S0[((size_t)c * BATCH + b) * NST + n] = s;
    s = fmaf(lL, s, z[c]);
  }
}

// ---------------------------------------------------------------------------
extern "C" void kernel_launch(void* const* d_in, const int* in_sizes, int n_in,
                              void* d_out, int out_size, void* d_ws, size_t ws_size,
                              hipStream_t stream) {
  const float* x  = (const float*)d_in[0];
  const float* ll = (const float*)d_in[1];
  const float* Bm = (const float*)d_in[2];
  const float* Cm = (const float*)d_in[3];

  char* ws = (char*)d_ws;
  float* lam  = (float*)(ws);
  float* lamL = (float*)(ws + 2048);
  bf16*  Bb   = (bf16*)(ws + 4096);
  bf16*  Cb   = (bf16*)(ws + 4096 + NST * INF * 2);
  float* Z    = (float*)(ws + 4096 + NST * INF * 2 + OUTF * NST * 2);
  float* S0   = (float*)((char*)Z + (size_t)NCH * BATCH * NST * 4);
  // total ws use: ~8.6 MB

  float* out = (float*)d_out;
  float* fin = out + (size_t)SEQ * BATCH * OUTF;

  k_prep<<<dim3(512), dim3(256), 0, stream>>>(ll, Bm, Cm, lam, lamL, Bb, Cb);
  k_pass<0><<<dim3(NBLK), dim3(512), 0, stream>>>(x, Bb, Cb, lam, S0, Z, out, fin);
  k_chain<<<dim3(BATCH, 4), dim3(128), 0, stream>>>(Z, lamL, S0);
  k_pass<1><<<dim3(NBLK), dim3(512), 0, stream>>>(x, Bb, Cb, lam, S0, Z, out, fin);
}